// Round 1
// baseline (1400.748 us; speedup 1.0000x reference)
//
#include <hip/hip_runtime.h>
#include <math.h>

// Problem constants
#define BATCH 32768
#define EMB   2048
#define KDIM  320      // 5*8*8
#define KACT  103      // ceil(0.05*2048)

// GEMM tiling
#define BM 16
#define BK 4
#define GTHREADS 512

// ---------------------------------------------------------------------------
// Kernel 0: transpose fc_w (2048 x 320) -> WT (320 x 2048) for coalesced
// k-major staging in the GEMM.
// ---------------------------------------------------------------------------
__global__ __launch_bounds__(256) void transpose_w_kernel(const float* __restrict__ W,
                                                          float* __restrict__ WT) {
  __shared__ float tile[32][33];  // +1 pad: conflict-free transpose
  const int k0 = blockIdx.x * 32;   // gridDim.x = 320/32 = 10
  const int n0 = blockIdx.y * 32;   // gridDim.y = 2048/32 = 64
  const int tx = threadIdx.x;       // 0..31
  const int ty = threadIdx.y;       // 0..7
  for (int i = ty; i < 32; i += 8)
    tile[i][tx] = W[(size_t)(n0 + i) * KDIM + k0 + tx];
  __syncthreads();
  for (int i = ty; i < 32; i += 8)
    WT[(size_t)(k0 + i) * EMB + n0 + tx] = tile[tx][i];
}

// ---------------------------------------------------------------------------
// Kernel 1: conv3x3(valid) + batchnorm + relu + maxpool3x3 stride3 (valid)
// One block per image; 320 threads = one per pooled output (c,y,x).
// Pooled cell (y,x) depends on input rows 3y..3y+4, cols 3x..3x+4.
// Accumulation: serial fma over (di,dj) ascending (im2col/BLAS order).
// BN: exact op order (s - mean) * inv + beta, contraction OFF so rounding
// matches an unfused reference (for beta=0/mean=0 it is unambiguous anyway).
// ---------------------------------------------------------------------------
__global__ __launch_bounds__(320) void conv_pool_kernel(const float* __restrict__ x,
                                                        const float* __restrict__ cw,
                                                        const float* __restrict__ gamma,
                                                        const float* __restrict__ beta,
                                                        const float* __restrict__ mean,
                                                        const float* __restrict__ var,
                                                        float* __restrict__ H) {
#pragma clang fp contract(off)
  __shared__ float xs[784];
  __shared__ float wv[45];
  __shared__ float inv_s[5], mu_s[5], be_s[5];
  const int b = blockIdx.x;
  const int t = threadIdx.x;

  for (int i = t; i < 784; i += 320) xs[i] = x[(size_t)b * 784 + i];
  if (t < 45) wv[t] = cw[t];
  if (t < 5) {
    inv_s[t] = gamma[t] / sqrtf(var[t] + 1e-5f);  // IEEE div & sqrt (no fast-math)
    mu_s[t] = mean[t];
    be_s[t] = beta[t];
  }
  __syncthreads();

  const int c  = t >> 6;       // channel 0..4
  const int p  = t & 63;
  const int py = p >> 3;       // pooled y 0..7
  const int px = p & 7;        // pooled x 0..7

  float xr[5][5];
#pragma unroll
  for (int i = 0; i < 5; ++i)
#pragma unroll
    for (int j = 0; j < 5; ++j)
      xr[i][j] = xs[(3 * py + i) * 28 + 3 * px + j];

  float wr[9];
#pragma unroll
  for (int i = 0; i < 9; ++i) wr[i] = wv[c * 9 + i];

  const float inv = inv_s[c], mu = mu_s[c], be = be_s[c];

  float mx = -__builtin_huge_valf();
#pragma unroll
  for (int ry = 0; ry < 3; ++ry)
#pragma unroll
    for (int rx = 0; rx < 3; ++rx) {
      float s = 0.0f;
#pragma unroll
      for (int di = 0; di < 3; ++di)
#pragma unroll
        for (int dj = 0; dj < 3; ++dj)
          s = __builtin_fmaf(xr[ry + di][rx + dj], wr[di * 3 + dj], s);
      float t1 = s - mu;
      float t2 = t1 * inv;
      float t3 = t2 + be;
      mx = fmaxf(mx, t3);
    }
  mx = fmaxf(mx, 0.0f);  // relu commutes with max

  H[(size_t)b * KDIM + t] = mx;
}

// ---------------------------------------------------------------------------
// Kernel 2: fused GEMM (z = H @ W^T) + per-row 103rd-largest threshold +
// binary write. One block = 16 full rows x all 2048 cols.
// Thread t holds acc[16][4] for n = 4t..4t+3 (micro-tile 16m x 4n).
// A staged once in LDS as [k][m] (broadcast reads); B staged per 4-k tile
// as [kk][n] (contiguous b128 reads, conflict-free).
// Accumulation: single serial fma chain over k=0..319 per element.
// Top-k: 4-pass radix-256 select on order-preserving uint32 mapping.
// ---------------------------------------------------------------------------
__global__ __launch_bounds__(GTHREADS) void gemm_topk_kernel(const float* __restrict__ H,
                                                             const float* __restrict__ WT,
                                                             float* __restrict__ out) {
  __shared__ __align__(16) float As[KDIM * BM];   // [k][m] 20 KB
  __shared__ __align__(16) float Bs[BK * EMB];    // [kk][n] 32 KB
  __shared__ unsigned prefix_s[BM];
  __shared__ unsigned rank_s[BM];
  unsigned* histo = (unsigned*)Bs;                // alias: Bs dead after k-loop

  const int t    = threadIdx.x;
  const int lane = t & 63;
  const int w    = t >> 6;                        // wave 0..7
  const int m0   = blockIdx.x * BM;
  const int nt   = t * 4;

  // Stage A: coalesced read along k, scatter to [k][m]
  for (int i = t; i < KDIM * BM; i += GTHREADS) {
    const int m = i / KDIM;
    const int k = i - m * KDIM;
    As[k * BM + m] = H[(size_t)(m0 + m) * KDIM + k];
  }
  if (t < BM) { prefix_s[t] = 0u; rank_s[t] = KACT; }

  float acc[BM][4];
#pragma unroll
  for (int m = 0; m < BM; ++m)
#pragma unroll
    for (int j = 0; j < 4; ++j) acc[m][j] = 0.0f;

  for (int kt = 0; kt < KDIM / BK; ++kt) {
    __syncthreads();  // covers A-staging (first iter) and Bs reuse
    // Stage B tile: straight 32 KB copy of WT[kt*BK .. +BK][0..2048]
    {
      const float4* src = (const float4*)(WT + (size_t)kt * BK * EMB);
      float4* dst = (float4*)Bs;
#pragma unroll
      for (int i = 0; i < (BK * EMB / 4) / GTHREADS; ++i)
        dst[t + i * GTHREADS] = src[t + i * GTHREADS];
    }
    __syncthreads();
#pragma unroll
    for (int kk = 0; kk < BK; ++kk) {
      const int k = kt * BK + kk;
      const float4* ap = (const float4*)(As + k * BM);
      const float4 a0 = ap[0], a1 = ap[1], a2 = ap[2], a3 = ap[3];
      const float4 b = *(const float4*)(Bs + kk * EMB + nt);
      const float av[BM] = {a0.x, a0.y, a0.z, a0.w, a1.x, a1.y, a1.z, a1.w,
                            a2.x, a2.y, a2.z, a2.w, a3.x, a3.y, a3.z, a3.w};
#pragma unroll
      for (int m = 0; m < BM; ++m) {
        acc[m][0] = __builtin_fmaf(av[m], b.x, acc[m][0]);
        acc[m][1] = __builtin_fmaf(av[m], b.y, acc[m][1]);
        acc[m][2] = __builtin_fmaf(av[m], b.z, acc[m][2]);
        acc[m][3] = __builtin_fmaf(av[m], b.w, acc[m][3]);
      }
    }
  }
  __syncthreads();  // all Bs reads done before histo aliasing

  // ---- radix-256 select of the KACT-th largest per row ----
  for (int pass = 0; pass < 4; ++pass) {
    const int shift = 24 - pass * 8;
    for (int i = t; i < BM * 256; i += GTHREADS) histo[i] = 0u;
    unsigned pref[BM];
#pragma unroll
    for (int m = 0; m < BM; ++m) pref[m] = prefix_s[m];
    __syncthreads();
#pragma unroll
    for (int m = 0; m < BM; ++m) {
#pragma unroll
      for (int j = 0; j < 4; ++j) {
        unsigned u = __float_as_uint(acc[m][j]);
        u = (u & 0x80000000u) ? ~u : (u | 0x80000000u);  // ascending order map
        const bool in = (pass == 0) || ((u >> (shift + 8)) == pref[m]);
        if (in) atomicAdd(&histo[m * 256 + ((u >> shift) & 255u)], 1u);
      }
    }
    __syncthreads();
    // Scan: wave w handles rows 2w, 2w+1. Lane l covers bins [4l,4l+4);
    // higher lane = higher-valued bins. Suffix-sum gives counts-above.
    for (int rr = 0; rr < 2; ++rr) {
      const int m = w * 2 + rr;
      const unsigned rank = rank_s[m];
      const uint4 c = *(const uint4*)(histo + m * 256 + lane * 4);
      const unsigned s = c.x + c.y + c.z + c.w;
      unsigned suf = s;
#pragma unroll
      for (int off = 1; off < 64; off <<= 1) {
        const unsigned o = __shfl_down(suf, off);
        if (lane + off < 64) suf += o;
      }
      const unsigned above = suf - s;  // counts in bins > 4*lane+3
      if (above < rank && rank <= suf) {  // exactly one lane hits
        unsigned bin, newr;
        if (above + c.w >= rank)                    { bin = lane * 4 + 3; newr = rank - above; }
        else if (above + c.w + c.z >= rank)         { bin = lane * 4 + 2; newr = rank - above - c.w; }
        else if (above + c.w + c.z + c.y >= rank)   { bin = lane * 4 + 1; newr = rank - above - c.w - c.z; }
        else                                        { bin = lane * 4 + 0; newr = rank - above - c.w - c.z - c.y; }
        prefix_s[m] = (prefix_s[m] << 8) | bin;
        rank_s[m] = newr;
      }
    }
    __syncthreads();
  }

  // prefix_s[m] now holds the exact uint-mapped 103rd-largest value
  unsigned thr[BM];
#pragma unroll
  for (int m = 0; m < BM; ++m) thr[m] = prefix_s[m];

#pragma unroll
  for (int m = 0; m < BM; ++m) {
    float4 o;
    float* op = (float*)&o;
#pragma unroll
    for (int j = 0; j < 4; ++j) {
      unsigned u = __float_as_uint(acc[m][j]);
      u = (u & 0x80000000u) ? ~u : (u | 0x80000000u);
      op[j] = (u >= thr[m]) ? 1.0f : 0.0f;  // same tie semantics as z >= topv[:,-1]
    }
    *(float4*)(out + (size_t)(m0 + m) * EMB + nt) = o;
  }
}

// ---------------------------------------------------------------------------
extern "C" void kernel_launch(void* const* d_in, const int* in_sizes, int n_in,
                              void* d_out, int out_size, void* d_ws, size_t ws_size,
                              hipStream_t stream) {
  const float* x      = (const float*)d_in[0];
  const float* conv_w = (const float*)d_in[1];
  const float* gamma  = (const float*)d_in[2];
  const float* beta   = (const float*)d_in[3];
  const float* mean   = (const float*)d_in[4];
  const float* var    = (const float*)d_in[5];
  const float* fc_w   = (const float*)d_in[6];
  float* out = (float*)d_out;

  // workspace layout: H (32768*320 f32 = 40 MB) | WT (320*2048 f32 = 2.5 MB)
  float* H  = (float*)d_ws;
  float* WT = (float*)d_ws + (size_t)BATCH * KDIM;

  transpose_w_kernel<<<dim3(KDIM / 32, EMB / 32), dim3(32, 8), 0, stream>>>(fc_w, WT);
  conv_pool_kernel<<<BATCH, 320, 0, stream>>>(x, conv_w, gamma, beta, mean, var, H);
  gemm_topk_kernel<<<BATCH / BM, GTHREADS, 0, stream>>>(H, WT, out);
}

// Round 2
// 996.170 us; speedup vs baseline: 1.4061x; 1.4061x over previous
//
#include <hip/hip_runtime.h>
#include <math.h>

// Problem constants
#define BATCH 32768
#define EMB   2048
#define KDIM  320      // 5*8*8
#define KACT  103      // ceil(0.05*2048)

// GEMM tiling
#define BM 16
#define GTHREADS 512

// Conv batching
#define CIMG 8

// ---------------------------------------------------------------------------
// Kernel 0: transpose fc_w (2048 x 320) -> WT (320 x 2048) for coalesced
// k-major reads in the GEMM.
// ---------------------------------------------------------------------------
__global__ __launch_bounds__(256) void transpose_w_kernel(const float* __restrict__ W,
                                                          float* __restrict__ WT) {
  __shared__ float tile[32][33];  // +1 pad: conflict-free transpose
  const int k0 = blockIdx.x * 32;   // gridDim.x = 320/32 = 10
  const int n0 = blockIdx.y * 32;   // gridDim.y = 2048/32 = 64
  const int tx = threadIdx.x;       // 0..31
  const int ty = threadIdx.y;       // 0..7
  for (int i = ty; i < 32; i += 8)
    tile[i][tx] = W[(size_t)(n0 + i) * KDIM + k0 + tx];
  __syncthreads();
  for (int i = ty; i < 32; i += 8)
    WT[(size_t)(k0 + i) * EMB + n0 + tx] = tile[tx][i];
}

// ---------------------------------------------------------------------------
// Kernel 1: conv3x3(valid) + batchnorm + relu + maxpool3x3 stride3 (valid)
// 8 images per 512-thread block. Thread t: image = t>>6, spatial pooled
// position = lane (py=lane>>3, px=lane&7), computes ALL 5 channels from one
// 5x5 input patch held in registers. Serial fma over (di,dj) ascending —
// same summation order as the round-1 PASSING kernel.
// ---------------------------------------------------------------------------
__global__ __launch_bounds__(512) void conv_pool_kernel(const float* __restrict__ x,
                                                        const float* __restrict__ cw,
                                                        const float* __restrict__ gamma,
                                                        const float* __restrict__ beta,
                                                        const float* __restrict__ mean,
                                                        const float* __restrict__ var,
                                                        float* __restrict__ H) {
#pragma clang fp contract(off)
  __shared__ float xs[CIMG * 784];
  __shared__ float wv[45];
  __shared__ float inv_s[5], mu_s[5], be_s[5];
  const int t  = threadIdx.x;
  const int b0 = blockIdx.x * CIMG;

  // Stage 8 images (25 KB) with float4 loads: 8*196 = 1568 float4
  {
    const float4* src = (const float4*)(x + (size_t)b0 * 784);
    float4* dst = (float4*)xs;
    for (int i = t; i < CIMG * 196; i += 512) dst[i] = src[i];
  }
  if (t < 45) wv[t] = cw[t];
  if (t < 5) {
    inv_s[t] = gamma[t] / sqrtf(var[t] + 1e-5f);  // IEEE div & sqrt
    mu_s[t] = mean[t];
    be_s[t] = beta[t];
  }
  __syncthreads();

  const int img  = t >> 6;
  const int lane = t & 63;
  const int py = lane >> 3;
  const int px = lane & 7;
  const float* xb = xs + img * 784;

  float xr[5][5];
#pragma unroll
  for (int i = 0; i < 5; ++i)
#pragma unroll
    for (int j = 0; j < 5; ++j)
      xr[i][j] = xb[(3 * py + i) * 28 + 3 * px + j];

  float wr[45];
#pragma unroll
  for (int i = 0; i < 45; ++i) wr[i] = wv[i];

  float res[5];
#pragma unroll
  for (int c = 0; c < 5; ++c) {
    const float inv = inv_s[c], mu = mu_s[c], be = be_s[c];
    float mx = -__builtin_huge_valf();
#pragma unroll
    for (int ry = 0; ry < 3; ++ry)
#pragma unroll
      for (int rx = 0; rx < 3; ++rx) {
        float s = 0.0f;
#pragma unroll
        for (int di = 0; di < 3; ++di)
#pragma unroll
          for (int dj = 0; dj < 3; ++dj)
            s = __builtin_fmaf(xr[ry + di][rx + dj], wr[c * 9 + di * 3 + dj], s);
        float t1 = s - mu;
        float t2 = t1 * inv;
        float t3 = t2 + be;
        mx = fmaxf(mx, t3);
      }
    res[c] = fmaxf(mx, 0.0f);  // relu commutes with max
  }

#pragma unroll
  for (int c = 0; c < 5; ++c)
    H[(size_t)(b0 + img) * KDIM + c * 64 + lane] = res[c];
}

// ---------------------------------------------------------------------------
// Kernel 2: fused GEMM (z = H @ W^T) + per-row 103rd-largest threshold +
// binary write. One block = 16 full rows x all 2048 cols; thread t owns
// acc[16][4] for n = 4t..4t+3.
//
// Round-2 structure: NO B staging in LDS. WT (2.5 MB) is L2-resident; each
// thread reads its fixed 16B column slice per k straight from global
// (coalesced: 8 KB contiguous per k across the block), with a one-iteration
// manual prefetch (4 k-rows ahead) so L2 latency hides under 256 FMAs.
// Only ONE barrier before the k-loop (A staging) and one after (histo alias).
// A in LDS [k][m], read as 4x b128 wave-broadcast per k.
// Accumulation: single serial fma chain over k=0..319 per element (exact
// match to the round-1 passing kernel).
// Top-k: 4-pass radix-256 select on order-preserving uint32 mapping; the
// histogram aliases As (16 KB <= 20 KB), so total LDS ~21 KB.
// ---------------------------------------------------------------------------
__global__ __launch_bounds__(GTHREADS) void gemm_topk_kernel(const float* __restrict__ H,
                                                             const float* __restrict__ WT,
                                                             float* __restrict__ out) {
  __shared__ __align__(16) float As[KDIM * BM];   // [k][m] 20 KB
  __shared__ unsigned prefix_s[BM];
  __shared__ unsigned rank_s[BM];
  unsigned* histo = (unsigned*)As;                // alias: As dead after k-loop

  const int t    = threadIdx.x;
  const int lane = t & 63;
  const int w    = t >> 6;                        // wave 0..7
  const int m0   = blockIdx.x * BM;
  const int nt   = t * 4;

  // Stage A: coalesced read along k, scatter to [k][m]
  for (int i = t; i < KDIM * BM; i += GTHREADS) {
    const int m = i / KDIM;
    const int k = i - m * KDIM;
    As[k * BM + m] = H[(size_t)(m0 + m) * KDIM + k];
  }
  if (t < BM) { prefix_s[t] = 0u; rank_s[t] = KACT; }
  __syncthreads();

  float acc[BM][4];
#pragma unroll
  for (int m = 0; m < BM; ++m)
#pragma unroll
    for (int j = 0; j < 4; ++j) acc[m][j] = 0.0f;

  const float* wp = WT + nt;
  float4 nb0 = *(const float4*)(wp + 0 * EMB);
  float4 nb1 = *(const float4*)(wp + 1 * EMB);
  float4 nb2 = *(const float4*)(wp + 2 * EMB);
  float4 nb3 = *(const float4*)(wp + 3 * EMB);

  for (int k4 = 0; k4 < KDIM / 4; ++k4) {
    const float4 b0 = nb0, b1 = nb1, b2 = nb2, b3 = nb3;
    if (k4 + 1 < KDIM / 4) {  // uniform branch; prefetch next 4 B-rows
      const float* wn = wp + (size_t)(k4 + 1) * 4 * EMB;
      nb0 = *(const float4*)(wn + 0 * EMB);
      nb1 = *(const float4*)(wn + 1 * EMB);
      nb2 = *(const float4*)(wn + 2 * EMB);
      nb3 = *(const float4*)(wn + 3 * EMB);
    }
#pragma unroll
    for (int kk = 0; kk < 4; ++kk) {
      const float4* ap = (const float4*)(As + (4 * k4 + kk) * BM);
      const float4 a0 = ap[0], a1 = ap[1], a2 = ap[2], a3 = ap[3];
      const float av[BM] = {a0.x, a0.y, a0.z, a0.w, a1.x, a1.y, a1.z, a1.w,
                            a2.x, a2.y, a2.z, a2.w, a3.x, a3.y, a3.z, a3.w};
      const float4 bb = (kk == 0) ? b0 : (kk == 1) ? b1 : (kk == 2) ? b2 : b3;
#pragma unroll
      for (int m = 0; m < BM; ++m) {
        acc[m][0] = __builtin_fmaf(av[m], bb.x, acc[m][0]);
        acc[m][1] = __builtin_fmaf(av[m], bb.y, acc[m][1]);
        acc[m][2] = __builtin_fmaf(av[m], bb.z, acc[m][2]);
        acc[m][3] = __builtin_fmaf(av[m], bb.w, acc[m][3]);
      }
    }
  }
  __syncthreads();  // all As reads done before histo aliasing

  // ---- radix-256 select of the KACT-th largest per row ----
  for (int pass = 0; pass < 4; ++pass) {
    const int shift = 24 - pass * 8;
    for (int i = t; i < BM * 256; i += GTHREADS) histo[i] = 0u;
    unsigned pref[BM];
#pragma unroll
    for (int m = 0; m < BM; ++m) pref[m] = prefix_s[m];
    __syncthreads();
#pragma unroll
    for (int m = 0; m < BM; ++m) {
#pragma unroll
      for (int j = 0; j < 4; ++j) {
        unsigned u = __float_as_uint(acc[m][j]);
        u = (u & 0x80000000u) ? ~u : (u | 0x80000000u);  // ascending order map
        const bool in = (pass == 0) || ((u >> (shift + 8)) == pref[m]);
        if (in) atomicAdd(&histo[m * 256 + ((u >> shift) & 255u)], 1u);
      }
    }
    __syncthreads();
    // Scan: wave w handles rows 2w, 2w+1. Lane l covers bins [4l,4l+4);
    // higher lane = higher-valued bins. Suffix-sum gives counts-above.
    for (int rr = 0; rr < 2; ++rr) {
      const int m = w * 2 + rr;
      const unsigned rank = rank_s[m];
      const uint4 c = *(const uint4*)(histo + m * 256 + lane * 4);
      const unsigned s = c.x + c.y + c.z + c.w;
      unsigned suf = s;
#pragma unroll
      for (int off = 1; off < 64; off <<= 1) {
        const unsigned o = __shfl_down(suf, off);
        if (lane + off < 64) suf += o;
      }
      const unsigned above = suf - s;  // counts in bins > 4*lane+3
      if (above < rank && rank <= suf) {  // exactly one lane hits
        unsigned bin, newr;
        if (above + c.w >= rank)                    { bin = lane * 4 + 3; newr = rank - above; }
        else if (above + c.w + c.z >= rank)         { bin = lane * 4 + 2; newr = rank - above - c.w; }
        else if (above + c.w + c.z + c.y >= rank)   { bin = lane * 4 + 1; newr = rank - above - c.w - c.z; }
        else                                        { bin = lane * 4 + 0; newr = rank - above - c.w - c.z - c.y; }
        prefix_s[m] = (prefix_s[m] << 8) | bin;
        rank_s[m] = newr;
      }
    }
    __syncthreads();
  }

  // prefix_s[m] now holds the exact uint-mapped 103rd-largest value
  unsigned thr[BM];
#pragma unroll
  for (int m = 0; m < BM; ++m) thr[m] = prefix_s[m];

#pragma unroll
  for (int m = 0; m < BM; ++m) {
    float4 o;
    float* op = (float*)&o;
#pragma unroll
    for (int j = 0; j < 4; ++j) {
      unsigned u = __float_as_uint(acc[m][j]);
      u = (u & 0x80000000u) ? ~u : (u | 0x80000000u);
      op[j] = (u >= thr[m]) ? 1.0f : 0.0f;  // same tie semantics as z >= topv[:,-1]
    }
    *(float4*)(out + (size_t)(m0 + m) * EMB + nt) = o;
  }
}

// ---------------------------------------------------------------------------
extern "C" void kernel_launch(void* const* d_in, const int* in_sizes, int n_in,
                              void* d_out, int out_size, void* d_ws, size_t ws_size,
                              hipStream_t stream) {
  const float* x      = (const float*)d_in[0];
  const float* conv_w = (const float*)d_in[1];
  const float* gamma  = (const float*)d_in[2];
  const float* beta   = (const float*)d_in[3];
  const float* mean   = (const float*)d_in[4];
  const float* var    = (const float*)d_in[5];
  const float* fc_w   = (const float*)d_in[6];
  float* out = (float*)d_out;

  // workspace layout: H (32768*320 f32 = 40 MB) | WT (320*2048 f32 = 2.5 MB)
  float* H  = (float*)d_ws;
  float* WT = (float*)d_ws + (size_t)BATCH * KDIM;

  transpose_w_kernel<<<dim3(KDIM / 32, EMB / 32), dim3(32, 8), 0, stream>>>(fc_w, WT);
  conv_pool_kernel<<<BATCH / CIMG, 512, 0, stream>>>(x, conv_w, gamma, beta, mean, var, H);
  gemm_topk_kernel<<<BATCH / BM, GTHREADS, 0, stream>>>(H, WT, out);
}

// Round 3
// 854.408 us; speedup vs baseline: 1.6394x; 1.1659x over previous
//
#include <hip/hip_runtime.h>
#include <math.h>

// Problem constants
#define BATCH 32768
#define EMB   2048
#define KDIM  320      // 5*8*8
#define KACT  103      // ceil(0.05*2048)

// GEMM tiling
#define BM 16
#define GTHREADS 512

// Conv batching
#define CIMG 16

// ---------------------------------------------------------------------------
// Kernel 0: transpose fc_w (2048 x 320) -> WT (320 x 2048) for coalesced
// k-major reads in the GEMM.
// ---------------------------------------------------------------------------
__global__ __launch_bounds__(256) void transpose_w_kernel(const float* __restrict__ W,
                                                          float* __restrict__ WT) {
  __shared__ float tile[32][33];  // +1 pad: conflict-free transpose
  const int k0 = blockIdx.x * 32;   // gridDim.x = 320/32 = 10
  const int n0 = blockIdx.y * 32;   // gridDim.y = 2048/32 = 64
  const int tx = threadIdx.x;       // 0..31
  const int ty = threadIdx.y;       // 0..7
  for (int i = ty; i < 32; i += 8)
    tile[i][tx] = W[(size_t)(n0 + i) * KDIM + k0 + tx];
  __syncthreads();
  for (int i = ty; i < 32; i += 8)
    WT[(size_t)(k0 + i) * EMB + n0 + tx] = tile[tx][i];
}

// ---------------------------------------------------------------------------
// Kernel 1: conv3x3(valid) + batchnorm + relu + maxpool3x3 stride3 (valid).
// 16 images per 512-thread block; thread (i0=t>>6, lane) processes images
// 2*i0 and 2*i0+1 sequentially (register reuse). Results staged in LDS
// (k-major, pad 17) then written to Ht[k][batch] in 64B-contiguous runs of
// 16 consecutive batch indices — coalesced k-major output for the GEMM's
// scalar A-loads. FMA order identical to the round-1/2 PASSING kernels.
// ---------------------------------------------------------------------------
__global__ __launch_bounds__(512) void conv_pool_kernel(const float* __restrict__ x,
                                                        const float* __restrict__ cw,
                                                        const float* __restrict__ gamma,
                                                        const float* __restrict__ beta,
                                                        const float* __restrict__ mean,
                                                        const float* __restrict__ var,
                                                        float* __restrict__ Ht) {
#pragma clang fp contract(off)
  __shared__ float xs[CIMG * 784];       // 50 KB
  __shared__ float hs[KDIM * 17];        // k-major staging, pad 17 (~21 KB)
  __shared__ float wv[45];
  __shared__ float inv_s[5], mu_s[5], be_s[5];
  const int t  = threadIdx.x;
  const int b0 = blockIdx.x * CIMG;

  // Stage 16 images (50 KB) with float4 loads: 16*196 = 3136 float4
  {
    const float4* src = (const float4*)(x + (size_t)b0 * 784);
    float4* dst = (float4*)xs;
    for (int i = t; i < CIMG * 196; i += 512) dst[i] = src[i];
  }
  if (t < 45) wv[t] = cw[t];
  if (t < 5) {
    inv_s[t] = gamma[t] / sqrtf(var[t] + 1e-5f);  // IEEE div & sqrt
    mu_s[t] = mean[t];
    be_s[t] = beta[t];
  }
  __syncthreads();

  const int i0   = t >> 6;
  const int lane = t & 63;
  const int py = lane >> 3;
  const int px = lane & 7;

  for (int ii = 0; ii < 2; ++ii) {
    const int img = i0 * 2 + ii;
    const float* xb = xs + img * 784;

    float xr[5][5];
#pragma unroll
    for (int i = 0; i < 5; ++i)
#pragma unroll
      for (int j = 0; j < 5; ++j)
        xr[i][j] = xb[(3 * py + i) * 28 + 3 * px + j];

#pragma unroll
    for (int c = 0; c < 5; ++c) {
      float wr[9];
#pragma unroll
      for (int i = 0; i < 9; ++i) wr[i] = wv[c * 9 + i];
      const float inv = inv_s[c], mu = mu_s[c], be = be_s[c];
      float mx = -__builtin_huge_valf();
#pragma unroll
      for (int ry = 0; ry < 3; ++ry)
#pragma unroll
        for (int rx = 0; rx < 3; ++rx) {
          float s = 0.0f;
#pragma unroll
          for (int di = 0; di < 3; ++di)
#pragma unroll
            for (int dj = 0; dj < 3; ++dj)
              s = __builtin_fmaf(xr[ry + di][rx + dj], wr[di * 3 + dj], s);
          float t1 = s - mu;
          float t2 = t1 * inv;
          float t3 = t2 + be;
          mx = fmaxf(mx, t3);
        }
      hs[(c * 64 + lane) * 17 + img] = fmaxf(mx, 0.0f);  // relu commutes w/ max
    }
  }
  __syncthreads();

  // Write out k-major: consecutive idx -> img fastest -> 64B runs
  for (int idx = t; idx < KDIM * CIMG; idx += 512) {
    const int k = idx >> 4;
    const int img = idx & 15;
    Ht[(size_t)k * BATCH + b0 + img] = hs[k * 17 + img];
  }
}

// ---------------------------------------------------------------------------
// Kernel 2: fused GEMM (z = H @ W^T) + per-row 103rd-largest threshold +
// binary write. One block = 16 rows x 2048 cols; thread t owns acc[16][4]
// for n = 4t..4t+3.
//
// Round-3 structure: NO LDS in the k-loop at all, and NO barriers.
//  - A: Ht is k-major; the 16 A-values per k are a block-uniform 64B read
//    Ht[k*BATCH + m0 + m] -> scalar-cache s_load (or broadcast L1 line).
//  - B: per-thread fixed float4 column slice from L2-resident WT, one-
//    iteration manual prefetch.
// Accumulation: single serial fma chain over k=0..319 per element — exact
// match to the passing rounds.
// Top-k: 4-pass radix-256 select, dedicated 16 KB histogram.
// ---------------------------------------------------------------------------
__global__ __launch_bounds__(GTHREADS) void gemm_topk_kernel(const float* __restrict__ Ht,
                                                             const float* __restrict__ WT,
                                                             float* __restrict__ out) {
  __shared__ unsigned histo[BM * 256];   // 16 KB
  __shared__ unsigned prefix_s[BM];
  __shared__ unsigned rank_s[BM];

  const int t    = threadIdx.x;
  const int lane = t & 63;
  const int w    = t >> 6;               // wave 0..7
  const int m0   = blockIdx.x * BM;
  const int nt   = t * 4;

  if (t < BM) { prefix_s[t] = 0u; rank_s[t] = KACT; }

  float acc[BM][4];
#pragma unroll
  for (int m = 0; m < BM; ++m)
#pragma unroll
    for (int j = 0; j < 4; ++j) acc[m][j] = 0.0f;

  const float* Ap = Ht + m0;             // A(k,m) = Ap[k*BATCH + m], uniform
  const float* wp = WT + nt;
  float4 nb0 = *(const float4*)(wp + 0 * EMB);
  float4 nb1 = *(const float4*)(wp + 1 * EMB);
  float4 nb2 = *(const float4*)(wp + 2 * EMB);
  float4 nb3 = *(const float4*)(wp + 3 * EMB);

  for (int k4 = 0; k4 < KDIM / 4; ++k4) {
    const float4 b0 = nb0, b1 = nb1, b2 = nb2, b3 = nb3;
    if (k4 + 1 < KDIM / 4) {  // uniform branch; prefetch next 4 B-rows
      const float* wn = wp + (size_t)(k4 + 1) * 4 * EMB;
      nb0 = *(const float4*)(wn + 0 * EMB);
      nb1 = *(const float4*)(wn + 1 * EMB);
      nb2 = *(const float4*)(wn + 2 * EMB);
      nb3 = *(const float4*)(wn + 3 * EMB);
    }
#pragma unroll
    for (int kk = 0; kk < 4; ++kk) {
      const float* ak = Ap + (size_t)(4 * k4 + kk) * BATCH;
      float av[BM];
#pragma unroll
      for (int m = 0; m < BM; ++m) av[m] = ak[m];   // uniform -> s_load
      const float4 bb = (kk == 0) ? b0 : (kk == 1) ? b1 : (kk == 2) ? b2 : b3;
#pragma unroll
      for (int m = 0; m < BM; ++m) {
        acc[m][0] = __builtin_fmaf(av[m], bb.x, acc[m][0]);
        acc[m][1] = __builtin_fmaf(av[m], bb.y, acc[m][1]);
        acc[m][2] = __builtin_fmaf(av[m], bb.z, acc[m][2]);
        acc[m][3] = __builtin_fmaf(av[m], bb.w, acc[m][3]);
      }
    }
  }
  __syncthreads();  // prefix_s/rank_s init visible to all before select

  // ---- radix-256 select of the KACT-th largest per row ----
  for (int pass = 0; pass < 4; ++pass) {
    const int shift = 24 - pass * 8;
    for (int i = t; i < BM * 256; i += GTHREADS) histo[i] = 0u;
    unsigned pref[BM];
#pragma unroll
    for (int m = 0; m < BM; ++m) pref[m] = prefix_s[m];
    __syncthreads();
#pragma unroll
    for (int m = 0; m < BM; ++m) {
#pragma unroll
      for (int j = 0; j < 4; ++j) {
        unsigned u = __float_as_uint(acc[m][j]);
        u = (u & 0x80000000u) ? ~u : (u | 0x80000000u);  // ascending order map
        const bool in = (pass == 0) || ((u >> (shift + 8)) == pref[m]);
        if (in) atomicAdd(&histo[m * 256 + ((u >> shift) & 255u)], 1u);
      }
    }
    __syncthreads();
    // Scan: wave w handles rows 2w, 2w+1. Lane l covers bins [4l,4l+4);
    // higher lane = higher-valued bins. Suffix-sum gives counts-above.
    for (int rr = 0; rr < 2; ++rr) {
      const int m = w * 2 + rr;
      const unsigned rank = rank_s[m];
      const uint4 c = *(const uint4*)(histo + m * 256 + lane * 4);
      const unsigned s = c.x + c.y + c.z + c.w;
      unsigned suf = s;
#pragma unroll
      for (int off = 1; off < 64; off <<= 1) {
        const unsigned o = __shfl_down(suf, off);
        if (lane + off < 64) suf += o;
      }
      const unsigned above = suf - s;  // counts in bins > 4*lane+3
      if (above < rank && rank <= suf) {  // exactly one lane hits
        unsigned bin, newr;
        if (above + c.w >= rank)                    { bin = lane * 4 + 3; newr = rank - above; }
        else if (above + c.w + c.z >= rank)         { bin = lane * 4 + 2; newr = rank - above - c.w; }
        else if (above + c.w + c.z + c.y >= rank)   { bin = lane * 4 + 1; newr = rank - above - c.w - c.z; }
        else                                        { bin = lane * 4 + 0; newr = rank - above - c.w - c.z - c.y; }
        prefix_s[m] = (prefix_s[m] << 8) | bin;
        rank_s[m] = newr;
      }
    }
    __syncthreads();
  }

  // prefix_s[m] now holds the exact uint-mapped 103rd-largest value
  unsigned thr[BM];
#pragma unroll
  for (int m = 0; m < BM; ++m) thr[m] = prefix_s[m];

#pragma unroll
  for (int m = 0; m < BM; ++m) {
    float4 o;
    float* op = (float*)&o;
#pragma unroll
    for (int j = 0; j < 4; ++j) {
      unsigned u = __float_as_uint(acc[m][j]);
      u = (u & 0x80000000u) ? ~u : (u | 0x80000000u);
      op[j] = (u >= thr[m]) ? 1.0f : 0.0f;  // same tie semantics as z >= topv[:,-1]
    }
    *(float4*)(out + (size_t)(m0 + m) * EMB + nt) = o;
  }
}

// ---------------------------------------------------------------------------
extern "C" void kernel_launch(void* const* d_in, const int* in_sizes, int n_in,
                              void* d_out, int out_size, void* d_ws, size_t ws_size,
                              hipStream_t stream) {
  const float* x      = (const float*)d_in[0];
  const float* conv_w = (const float*)d_in[1];
  const float* gamma  = (const float*)d_in[2];
  const float* beta   = (const float*)d_in[3];
  const float* mean   = (const float*)d_in[4];
  const float* var    = (const float*)d_in[5];
  const float* fc_w   = (const float*)d_in[6];
  float* out = (float*)d_out;

  // workspace layout: Ht (320 x 32768 f32 = 40 MB, k-major) | WT (320 x 2048)
  float* Ht = (float*)d_ws;
  float* WT = (float*)d_ws + (size_t)KDIM * BATCH;

  transpose_w_kernel<<<dim3(KDIM / 32, EMB / 32), dim3(32, 8), 0, stream>>>(fc_w, WT);
  conv_pool_kernel<<<BATCH / CIMG, 512, 0, stream>>>(x, conv_w, gamma, beta, mean, var, Ht);
  gemm_topk_kernel<<<BATCH / BM, GTHREADS, 0, stream>>>(Ht, WT, out);
}